// Round 6
// baseline (448.631 us; speedup 1.0000x reference)
//
#include <hip/hip_runtime.h>

// x: (64,3,512,512) fp32 -> conv3x3 VALID + avgpool2x2 + sigmoid + per-batch sum.
// Fused stride-2 4x4 conv: w_eff[ky][kx] = 0.25*sum_{py,px in {0,1}} w[ky-py][kx-px].
//
// R5: latency fix. R4 was vmcnt-bound (real VALU occupancy ~20%: loads consumed
// right after issue). Now the 4-row x-window lives in registers (slots rotated by
// template-static parity), and each pooled row prefetches only its 2 FRESH rows
// ~1700 cycles ahead of first use. 32 independent acc chains kept (R3/R4 ILP win).

#define IC 3
#define OCH 16
#define HH 512
#define WW 512
#define SROWS 5
#define STRIPS 51  // 51 * 5 = 255 pooled rows

__device__ __forceinline__ float fast_sigmoid(float v) {
    float e = __expf(-v);                    // v_exp_f32
    return __builtin_amdgcn_rcpf(1.0f + e);  // v_rcp_f32
}

// d_ws layout: ws[(ic*4+ky)*64 + oc*4 + kx] for the 768 w_eff; ws[768+oc] = bias.
__global__ void build_weff(const float* __restrict__ w,
                           const float* __restrict__ bias,
                           float* __restrict__ ws)
{
    const int i = threadIdx.x;
    for (int idx = i; idx < IC * 4 * OCH * 4; idx += 256) {
        int kx = idx & 3;
        int oc = (idx >> 2) & 15;
        int icr = idx >> 6;           // ic*4 + ky
        int ic = icr >> 2;
        int ky = icr & 3;
        float s = 0.f;
#pragma unroll
        for (int py = 0; py < 2; ++py) {
            int r = ky - py;
            if (r < 0 || r > 2) continue;
#pragma unroll
            for (int px = 0; px < 2; ++px) {
                int c = kx - px;
                if (c < 0 || c > 2) continue;
                s += w[((oc * IC + ic) * 3 + r) * 3 + c];
            }
        }
        ws[idx] = 0.25f * s;
    }
    if (i < OCH) ws[IC * 4 * OCH * 4 + i] = bias[i];
}

// 32 FMA-group for one (ic, window-row): weights via wave-uniform s_load (1 SGPR/VOP2 fmac).
__device__ __forceinline__ void dot_row(const float4& a, const float2& t,
                                        const float* __restrict__ wp,
                                        float (&accA)[OCH], float (&accB)[OCH])
{
#pragma unroll
    for (int oc = 0; oc < OCH; ++oc) {
        const float w0 = wp[4 * oc + 0], w1 = wp[4 * oc + 1];
        const float w2 = wp[4 * oc + 2], w3 = wp[4 * oc + 3];
        accA[oc] = fmaf(a.x, w0, fmaf(a.y, w1, fmaf(a.z, w2, fmaf(a.w, w3, accA[oc]))));
        accB[oc] = fmaf(a.z, w0, fmaf(a.w, w1, fmaf(t.x, w2, fmaf(t.y, w3, accB[oc]))));
    }
}

// One pooled row. Window row i lives in slot S_i. Mid-step, prefetch the next
// pooled row's 2 fresh input rows (global rows yf, yf+1) into slots S0,S1 --
// those are consumed ~1700 cycles later in the NEXT step's rows-0,1 phase.
template<int S0, int S1, int S2, int S3>
__device__ __forceinline__ void srow_step(const float* __restrict__ xcb,
                                          const float* __restrict__ wws,
                                          const float (&bv)[OCH],
                                          float4 (&A)[IC][4], float2 (&T)[IC][4],
                                          int yf, int tail,
                                          float& lsA, float& lsB)
{
    float accA[OCH], accB[OCH];
#pragma unroll
    for (int oc = 0; oc < OCH; ++oc) { accA[oc] = bv[oc]; accB[oc] = bv[oc]; }

    // window rows 0,1
#pragma unroll
    for (int ic = 0; ic < IC; ++ic) {
        dot_row(A[ic][S0], T[ic][S0], wws + (ic * 4 + 0) * 64, accA, accB);
        dot_row(A[ic][S1], T[ic][S1], wws + (ic * 4 + 1) * 64, accA, accB);
    }

    // prefetch fresh rows into the just-freed slots (clamped at the image edge;
    // clamped data is only read by the final, discarded prefetch)
    {
        const int y0 = yf     > 511 ? 511 : yf;
        const int y1 = yf + 1 > 511 ? 511 : yf + 1;
#pragma unroll
        for (int ic = 0; ic < IC; ++ic) {
            const float* p0 = xcb + ((size_t)ic * HH + y0) * WW;
            const float* p1 = xcb + ((size_t)ic * HH + y1) * WW;
            A[ic][S0] = *(const float4*)p0;
            T[ic][S0] = *(const float2*)(p0 + tail);
            A[ic][S1] = *(const float4*)p1;
            T[ic][S1] = *(const float2*)(p1 + tail);
        }
    }

    // window rows 2,3
#pragma unroll
    for (int ic = 0; ic < IC; ++ic) {
        dot_row(A[ic][S2], T[ic][S2], wws + (ic * 4 + 2) * 64, accA, accB);
        dot_row(A[ic][S3], T[ic][S3], wws + (ic * 4 + 3) * 64, accA, accB);
    }

#pragma unroll
    for (int oc = 0; oc < OCH; ++oc) {
        lsA += fast_sigmoid(accA[oc]);
        lsB += fast_sigmoid(accB[oc]);
    }
}

__global__ __launch_bounds__(128)
void conv_pool_sig_sum(const float* __restrict__ x,
                       const float* __restrict__ wws,
                       float* __restrict__ out)
{
    const int tid = threadIdx.x;      // 0..127 == pooled-col-pair index
    const bool v1 = (tid < 127);      // pooled col 255 doesn't exist
    const int c0 = 4 * tid;           // input col base (max 508, 16B aligned)
    const int b = blockIdx.y;
    const int hp0 = blockIdx.x * SROWS;
    const int tail = v1 ? 4 : 0;      // right edge: re-read in-bounds, masked

    const float* xcb = x + (size_t)b * IC * HH * WW + c0;
    const float* bp = wws + IC * 4 * OCH * 4;

    float bv[OCH];
#pragma unroll
    for (int oc = 0; oc < OCH; ++oc) bv[oc] = bp[oc];  // uniform -> SGPRs

    // prologue: window for first pooled row of the strip, slots 0..3
    float4 A[IC][4];
    float2 T[IC][4];
    const int y0 = 2 * hp0;
#pragma unroll
    for (int ic = 0; ic < IC; ++ic)
#pragma unroll
        for (int r = 0; r < 4; ++r) {
            const float* p = xcb + ((size_t)ic * HH + y0 + r) * WW;
            A[ic][r] = *(const float4*)p;
            T[ic][r] = *(const float2*)(p + tail);
        }

    float lsA = 0.f, lsB = 0.f;
    int yn = y0 + 4;  // first fresh row pair

    srow_step<0, 1, 2, 3>(xcb, wws, bv, A, T, yn, tail, lsA, lsB); yn += 2;  // s=0
#pragma unroll 1
    for (int k = 0; k < (SROWS - 1) / 2; ++k) {
        srow_step<2, 3, 0, 1>(xcb, wws, bv, A, T, yn, tail, lsA, lsB); yn += 2;  // odd s
        srow_step<0, 1, 2, 3>(xcb, wws, bv, A, T, yn, tail, lsA, lsB); yn += 2;  // even s
    }

    lsA += v1 ? lsB : 0.f;

    // wave64 butterfly, one atomic per wave (2 per block)
#pragma unroll
    for (int off = 32; off > 0; off >>= 1)
        lsA += __shfl_xor(lsA, off, 64);
    if ((tid & 63) == 0) atomicAdd(out + b, lsA);
}

extern "C" void kernel_launch(void* const* d_in, const int* in_sizes, int n_in,
                              void* d_out, int out_size, void* d_ws, size_t ws_size,
                              hipStream_t stream) {
    const float* x = (const float*)d_in[0];
    const float* w = (const float*)d_in[1];
    const float* bias = (const float*)d_in[2];
    float* out = (float*)d_out;
    float* wws = (float*)d_ws;  // 784 floats ~ 3.1 KB

    hipMemsetAsync(out, 0, out_size * sizeof(float), stream);
    build_weff<<<1, 256, 0, stream>>>(w, bias, wws);

    dim3 grid(STRIPS, 64);  // 51 row-strips x 64 batches = 3264 blocks
    conv_pool_sig_sum<<<grid, 128, 0, stream>>>(x, wws, out);
}